// Round 4
// baseline (84021.631 us; speedup 1.0000x reference)
//
#include <hip/hip_runtime.h>
#include <stdint.h>

// RK4 ODE integrator: dx/dt = W2·tanh(W1·x + b1) + b2, 64 steps, t in [0,1].
// B=4096, D=1024, H=4096. bf16 MFMA 16x16x32, fp32 accumulate.
// GEMM1: h = tanh(x@W1^T + b1), TM=128/TN=128/BK=32 (m97 structure, ~3 blk/CU).
// GEMM2: k = h@W2^T + b2 + fused RK4 epilogue. Output [4096,1024] only makes
//        512 tiles of 128x64 = 2 blk/CU (grid-limited) -> split-K=2:
//        1024 blocks = 4 blk/CU, dual fp32 partial slices, parity-atomic
//        last-block combine (fence-release/acquire; no spin, G16-safe).

typedef __attribute__((ext_vector_type(8))) __bf16 bf16x8;
typedef __attribute__((ext_vector_type(4))) float floatx4;

#define TM 128

__device__ __forceinline__ unsigned short f2bf(float f) {
  union { float f; unsigned u; } v; v.f = f;
  unsigned r = v.u + 0x7fffu + ((v.u >> 16) & 1u);  // RNE
  return (unsigned short)(r >> 16);
}

__device__ __forceinline__ float tanh_fast(float x) {
  float cx = fminf(15.0f, fmaxf(-15.0f, x));
  float e = __expf(2.0f * cx);                       // v_exp_f32
  return fmaf(-2.0f, __builtin_amdgcn_rcpf(e + 1.0f), 1.0f);
}

__device__ __forceinline__ void async16(const unsigned short* g, unsigned short* l) {
  // direct global->LDS, 16B/lane; LDS dest = wave-uniform base + lane*16
  __builtin_amdgcn_global_load_lds(
      (__attribute__((address_space(1))) void*)(g),
      (__attribute__((address_space(3))) void*)(l),
      16, 0, 0);
}

// EPI: 0 = GEMM1 (bias+tanh -> bf16 hOut)
//      1 = GEMM2 rk4 first  (xacc = xf + aacc*k ; xb = bf16(xf + cnext*k))
//      2 = GEMM2 rk4 mid    (xacc += aacc*k    ; xb = bf16(xf + cnext*k))
//      3 = GEMM2 rk4 last   (xf = xacc + aacc*k; xb = bf16(xf))
template <int TN, int BKT, int EPI, int SPLITK, int MINW>
__global__ __launch_bounds__(256, MINW) void gemm_bt(
    const unsigned short* __restrict__ A,   // [M,K] bf16 row-major
    const unsigned short* __restrict__ Bw,  // [N,K] bf16 row-major (B^T form)
    const float* __restrict__ bias,         // [N]
    int K, int N,
    unsigned short* __restrict__ hOut,      // EPI==0: [M,N] bf16
    const float* xf_in, float* xacc, float* xf_out, unsigned short* xb,
    float aacc, float cnext,
    float* __restrict__ part, int* __restrict__ cnt) {
  constexpr int NJ = TN / 32;               // acc tiles in n per wave
  constexpr int KH = BKT / 32;              // k-halves per LDS tile
  __shared__ unsigned short As[TM * BKT];
  __shared__ unsigned short Bs[TN * BKT];
  __shared__ int sLast;

  const int tid  = threadIdx.x;
  const int lane = tid & 63;
  const int wv   = tid >> 6;          // 4 waves
  const int bm   = blockIdx.y * TM;
  const int bn   = blockIdx.x * TN;
  const int kz   = (SPLITK == 2) ? blockIdx.z : 0;
  const int Kc   = (SPLITK == 2) ? (K >> 1) : K;   // K handled per block

  // --- compute coords ---
  const int wm   = (wv >> 1) * 64;
  const int wn   = (wv & 1) * (TN / 2);
  const int lrow = lane & 15;         // A m-index / B n-index / C col
  const int lk   = lane >> 4;         // k-quad; C row-group

  floatx4 acc[4][NJ];
#pragma unroll
  for (int i = 0; i < 4; ++i)
#pragma unroll
    for (int j = 0; j < NJ; ++j) acc[i][j] = (floatx4){0.f, 0.f, 0.f, 0.f};

  // --- staging coords: one async16 = 64 lanes x 16B = 1 KB ---
  // BKT=32: 16 rows x 32 cols.  BKT=64: 8 rows x 64 cols.
  const int sr = (BKT == 32) ? (lane >> 2) : (lane >> 3);
  const int sc = (BKT == 32) ? ((lane & 3) << 3) : ((lane & 7) << 3);
  const int rpc = (BKT == 32) ? 16 : 8;     // rows per async16 call
  const int arb = wv * (TM / 4);            // A rows per wave
  const int brb = wv * (TN / 4);            // B rows per wave
  constexpr int NCA = (TM / 4 == 32) ? ((BKT == 32) ? 2 : 4) : ((BKT == 32) ? 1 : 2);
  constexpr int NCB = (TN / 4 == 32) ? ((BKT == 32) ? 2 : 4) : ((BKT == 32) ? 1 : 2);

  const unsigned short* pA = A  + (size_t)(bm + arb + sr) * K + (size_t)kz * Kc + sc;
  const unsigned short* pB = Bw + (size_t)(bn + brb + sr) * K + (size_t)kz * Kc + sc;

  for (int k0 = 0; k0 < Kc; k0 += BKT) {
#pragma unroll
    for (int c = 0; c < NCA; ++c)
      async16(pA + (size_t)(c * rpc) * K, &As[(arb + c * rpc) * BKT]);
#pragma unroll
    for (int c = 0; c < NCB; ++c)
      async16(pB + (size_t)(c * rpc) * K, &Bs[(brb + c * rpc) * BKT]);
    pA += BKT; pB += BKT;
    asm volatile("s_waitcnt vmcnt(0)" ::: "memory");
    __syncthreads();

#pragma unroll
    for (int kh = 0; kh < KH; ++kh) {
      bf16x8 aF[4], bF[NJ];
#pragma unroll
      for (int i = 0; i < 4; ++i)
        aF[i] = *(const bf16x8*)(&As[(wm + i * 16 + lrow) * BKT + kh * 32 + lk * 8]);
#pragma unroll
      for (int j = 0; j < NJ; ++j)
        bF[j] = *(const bf16x8*)(&Bs[(wn + j * 16 + lrow) * BKT + kh * 32 + lk * 8]);
#pragma unroll
      for (int i = 0; i < 4; ++i)
#pragma unroll
        for (int j = 0; j < NJ; ++j)
          acc[i][j] = __builtin_amdgcn_mfma_f32_16x16x32_bf16(aF[i], bF[j], acc[i][j], 0, 0, 0);
    }
    __syncthreads();
  }

  // --- split-K combine: store own slice, parity atomic, last block proceeds ---
  const float* other = nullptr;
  if constexpr (SPLITK == 2) {
    const size_t MN = (size_t)gridDim.y * TM * N;
    float* slice = part + (size_t)kz * MN;
#pragma unroll
    for (int j = 0; j < NJ; ++j) {
      const int col = bn + wn + j * 16 + lrow;
#pragma unroll
      for (int i = 0; i < 4; ++i) {
        const int row0 = bm + wm + i * 16 + lk * 4;
#pragma unroll
        for (int r = 0; r < 4; ++r)
          slice[(size_t)(row0 + r) * N + col] = acc[i][j][r];
      }
    }
    __threadfence();            // release: my stores visible before my signal
    __syncthreads();
    if (tid == 0)
      sLast = (atomicAdd(&cnt[blockIdx.y * gridDim.x + blockIdx.x], 1) & 1);
    __syncthreads();
    if (!sLast) return;         // first finisher exits; no spinning
    __threadfence();            // acquire: other slice now visible
    other = part + (size_t)(1 - kz) * MN;
  }

  // --- epilogue --- C/D layout: col = lane&15, row = (lane>>4)*4 + r (m89-verified)
#pragma unroll
  for (int j = 0; j < NJ; ++j) {
    const int col = bn + wn + j * 16 + lrow;
    const float bcol = bias[col];
#pragma unroll
    for (int i = 0; i < 4; ++i) {
      const int row0 = bm + wm + i * 16 + lk * 4;
#pragma unroll
      for (int r = 0; r < 4; ++r) {
        const size_t idx = (size_t)(row0 + r) * N + col;
        float v = acc[i][j][r] + bcol;
        if constexpr (SPLITK == 2) v += other[idx];
        if constexpr (EPI == 0) {
          hOut[idx] = f2bf(tanh_fast(v));
        } else if constexpr (EPI == 1) {
          const float xv = xf_in[idx];
          xacc[idx] = fmaf(aacc, v, xv);
          xb[idx] = f2bf(fmaf(cnext, v, xv));
        } else if constexpr (EPI == 2) {
          const float xv = xf_in[idx];
          xacc[idx] = fmaf(aacc, v, xacc[idx]);
          xb[idx] = f2bf(fmaf(cnext, v, xv));
        } else {
          const float xn = fmaf(aacc, v, xacc[idx]);
          xf_out[idx] = xn;
          xb[idx] = f2bf(xn);
        }
      }
    }
  }
}

__global__ void cvt_kernel(const float* __restrict__ s, unsigned short* __restrict__ d, int n4) {
  int i = blockIdx.x * 256 + threadIdx.x;
  if (i < n4) {
    float4 v = ((const float4*)s)[i];
    ((ushort4*)d)[i] = make_ushort4(f2bf(v.x), f2bf(v.y), f2bf(v.z), f2bf(v.w));
  }
}

__global__ void initx_kernel(const float* __restrict__ s, float* __restrict__ xf,
                             unsigned short* __restrict__ xb, int n4) {
  int i = blockIdx.x * 256 + threadIdx.x;
  if (i < n4) {
    float4 v = ((const float4*)s)[i];
    ((float4*)xf)[i] = v;
    ((ushort4*)xb)[i] = make_ushort4(f2bf(v.x), f2bf(v.y), f2bf(v.z), f2bf(v.w));
  }
}

extern "C" void kernel_launch(void* const* d_in, const int* in_sizes, int n_in,
                              void* d_out, int out_size, void* d_ws, size_t ws_size,
                              hipStream_t stream) {
  const float* x  = (const float*)d_in[0];
  const float* W1 = (const float*)d_in[1];
  const float* b1 = (const float*)d_in[2];
  const float* W2 = (const float*)d_in[3];
  const float* b2 = (const float*)d_in[4];
  const int H = in_sizes[2];            // 4096
  const int D = in_sizes[4];            // 1024
  const int B = in_sizes[0] / D;        // 4096

  // workspace layout: W1b | W2b | xb | hb | xacc | part[2] | cnt  (~104 MB)
  unsigned short* W1b = (unsigned short*)d_ws;
  unsigned short* W2b = W1b + (size_t)H * D;
  unsigned short* xb  = W2b + (size_t)D * H;
  unsigned short* hb  = xb + (size_t)B * D;
  float* xacc = (float*)(hb + (size_t)B * H);
  float* part = xacc + (size_t)B * D;
  int*   cnt  = (int*)(part + 2 * (size_t)B * D);
  float* xf   = (float*)d_out;          // fp32 state lives in d_out

  const size_t need = (size_t)((char*)(cnt + (D / 64) * (B / TM)) - (char*)d_ws);
  const bool splitk = (ws_size >= need);

  const float dt = 1.0f / 64.0f;

  int n4 = (H * D) / 4;
  cvt_kernel<<<dim3((n4 + 255) / 256), dim3(256), 0, stream>>>(W1, W1b, n4);
  cvt_kernel<<<dim3((n4 + 255) / 256), dim3(256), 0, stream>>>(W2, W2b, n4);
  int m4 = (B * D) / 4;
  initx_kernel<<<dim3((m4 + 255) / 256), dim3(256), 0, stream>>>(x, xf, xb, m4);

  dim3 blk(256, 1, 1);
  dim3 g1(H / 128, B / TM, 1);          // 32 x 32, TN=128 BK=32
  dim3 g2s(D / 64, B / TM, 2);          // 16 x 32 x 2, split-K
  dim3 g2f(D / 64, B / TM, 1);          // fallback, no split

#define G1()            gemm_bt<128, 32, 0, 1, 2><<<g1, blk, 0, stream>>>( \
      xb, W1b, b1, D, H, hb, nullptr, nullptr, nullptr, nullptr, 0.f, 0.f, nullptr, nullptr)
#define G2(EPI, aa, cn) do { if (splitk) \
      gemm_bt<64, 64, EPI, 2, 4><<<g2s, blk, 0, stream>>>( \
        hb, W2b, b2, H, D, nullptr, xf, xacc, xf, xb, (aa), (cn), part, cnt); \
    else \
      gemm_bt<64, 64, EPI, 1, 2><<<g2f, blk, 0, stream>>>( \
        hb, W2b, b2, H, D, nullptr, xf, xacc, xf, xb, (aa), (cn), nullptr, nullptr); } while (0)

  for (int s = 0; s < 64; ++s) {
    G1(); G2(1, dt / 6.f, dt / 2.f);    // k1
    G1(); G2(2, dt / 3.f, dt / 2.f);    // k2
    G1(); G2(2, dt / 3.f, dt);          // k3
    G1(); G2(3, dt / 6.f, 0.f);         // k4
  }
#undef G1
#undef G2
}

// Round 5
// 80897.772 us; speedup vs baseline: 1.0386x; 1.0386x over previous
//
#include <hip/hip_runtime.h>
#include <stdint.h>

// RK4 ODE integrator: dx/dt = W2·tanh(W1·x + b1) + b2, 64 steps, t in [0,1].
// B=4096, D=1024, H=4096. bf16 MFMA 16x16x32, fp32 accumulate.
// GEMM1: h = tanh(x@W1^T + b1), TM=128/TN=128/BK=32 (m97 structure).
// GEMM2: k = h@W2^T + b2 + fused RK4 epilogue. Output [4096,1024] only makes
//        512 tiles of 128x64 (grid-limited, 2 blk/CU) -> split-K=2:
//        1024 blocks, dual fp32 partial slices (per-tile blocked, lane-major,
//        coalesced), parity-atomic last-block combine (no spin, G16-safe).
// R4 lesson: __launch_bounds__(256,4) (128-VGPR cap) spilled in the K-loop
//        -> 84 ms. Split kernels now MINW=2 (no cap).

typedef __attribute__((ext_vector_type(8))) __bf16 bf16x8;
typedef __attribute__((ext_vector_type(4))) float floatx4;

#define TM 128

__device__ __forceinline__ unsigned short f2bf(float f) {
  union { float f; unsigned u; } v; v.f = f;
  unsigned r = v.u + 0x7fffu + ((v.u >> 16) & 1u);  // RNE
  return (unsigned short)(r >> 16);
}

__device__ __forceinline__ float tanh_fast(float x) {
  float cx = fminf(15.0f, fmaxf(-15.0f, x));
  float e = __expf(2.0f * cx);                       // v_exp_f32
  return fmaf(-2.0f, __builtin_amdgcn_rcpf(e + 1.0f), 1.0f);
}

__device__ __forceinline__ void async16(const unsigned short* g, unsigned short* l) {
  // direct global->LDS, 16B/lane; LDS dest = wave-uniform base + lane*16
  __builtin_amdgcn_global_load_lds(
      (__attribute__((address_space(1))) void*)(g),
      (__attribute__((address_space(3))) void*)(l),
      16, 0, 0);
}

// EPI: 0 = GEMM1 (bias+tanh -> bf16 hOut)
//      1 = GEMM2 rk4 first  (xacc = xf + aacc*k ; xb = bf16(xf + cnext*k))
//      2 = GEMM2 rk4 mid    (xacc += aacc*k    ; xb = bf16(xf + cnext*k))
//      3 = GEMM2 rk4 last   (xf = xacc + aacc*k; xb = bf16(xf))
template <int TN, int BKT, int EPI, int SPLITK, int MINW>
__global__ __launch_bounds__(256, MINW) void gemm_bt(
    const unsigned short* __restrict__ A,   // [M,K] bf16 row-major
    const unsigned short* __restrict__ Bw,  // [N,K] bf16 row-major (B^T form)
    const float* __restrict__ bias,         // [N]
    int K, int N,
    unsigned short* __restrict__ hOut,      // EPI==0: [M,N] bf16
    const float* xf_in, float* xacc, float* xf_out, unsigned short* xb,
    float aacc, float cnext,
    float* __restrict__ part, int* __restrict__ cnt) {
  constexpr int NJ = TN / 32;               // acc tiles in n per wave
  constexpr int KH = BKT / 32;              // k-halves per LDS tile
  __shared__ unsigned short As[TM * BKT];
  __shared__ unsigned short Bs[TN * BKT];
  __shared__ int sLast;

  const int tid  = threadIdx.x;
  const int lane = tid & 63;
  const int wv   = tid >> 6;          // 4 waves
  const int bm   = blockIdx.y * TM;
  const int bn   = blockIdx.x * TN;
  const int kz   = (SPLITK == 2) ? blockIdx.z : 0;
  const int Kc   = (SPLITK == 2) ? (K >> 1) : K;   // K handled per block

  // --- compute coords ---
  const int wm   = (wv >> 1) * 64;
  const int wn   = (wv & 1) * (TN / 2);
  const int lrow = lane & 15;         // A m-index / B n-index / C col
  const int lk   = lane >> 4;         // k-quad; C row-group

  floatx4 acc[4][NJ];
#pragma unroll
  for (int i = 0; i < 4; ++i)
#pragma unroll
    for (int j = 0; j < NJ; ++j) acc[i][j] = (floatx4){0.f, 0.f, 0.f, 0.f};

  // --- staging coords: one async16 = 64 lanes x 16B = 1 KB ---
  // BKT=32: 16 rows x 32 cols.  BKT=64: 8 rows x 64 cols.
  const int sr = (BKT == 32) ? (lane >> 2) : (lane >> 3);
  const int sc = (BKT == 32) ? ((lane & 3) << 3) : ((lane & 7) << 3);
  const int rpc = (BKT == 32) ? 16 : 8;     // rows per async16 call
  const int arb = wv * (TM / 4);            // A rows per wave
  const int brb = wv * (TN / 4);            // B rows per wave
  constexpr int NCA = (TM / 4 == 32) ? ((BKT == 32) ? 2 : 4) : ((BKT == 32) ? 1 : 2);
  constexpr int NCB = (TN / 4 == 32) ? ((BKT == 32) ? 2 : 4) : ((BKT == 32) ? 1 : 2);

  const unsigned short* pA = A  + (size_t)(bm + arb + sr) * K + (size_t)kz * Kc + sc;
  const unsigned short* pB = Bw + (size_t)(bn + brb + sr) * K + (size_t)kz * Kc + sc;

  for (int k0 = 0; k0 < Kc; k0 += BKT) {
#pragma unroll
    for (int c = 0; c < NCA; ++c)
      async16(pA + (size_t)(c * rpc) * K, &As[(arb + c * rpc) * BKT]);
#pragma unroll
    for (int c = 0; c < NCB; ++c)
      async16(pB + (size_t)(c * rpc) * K, &Bs[(brb + c * rpc) * BKT]);
    pA += BKT; pB += BKT;
    asm volatile("s_waitcnt vmcnt(0)" ::: "memory");
    __syncthreads();

#pragma unroll
    for (int kh = 0; kh < KH; ++kh) {
      bf16x8 aF[4], bF[NJ];
#pragma unroll
      for (int i = 0; i < 4; ++i)
        aF[i] = *(const bf16x8*)(&As[(wm + i * 16 + lrow) * BKT + kh * 32 + lk * 8]);
#pragma unroll
      for (int j = 0; j < NJ; ++j)
        bF[j] = *(const bf16x8*)(&Bs[(wn + j * 16 + lrow) * BKT + kh * 32 + lk * 8]);
#pragma unroll
      for (int i = 0; i < 4; ++i)
#pragma unroll
        for (int j = 0; j < NJ; ++j)
          acc[i][j] = __builtin_amdgcn_mfma_f32_16x16x32_bf16(aF[i], bF[j], acc[i][j], 0, 0, 0);
    }
    __syncthreads();
  }

  // --- split-K combine: blocked lane-major partial slices, coalesced ---
  const float* other = nullptr;
  if constexpr (SPLITK == 2) {
    const size_t MN = (size_t)gridDim.y * gridDim.x * (TM * TN);
    const int tileIdx = blockIdx.y * gridDim.x + blockIdx.x;
    float* slice = part + (size_t)kz * MN + (size_t)tileIdx * (TM * TN);
#pragma unroll
    for (int j = 0; j < NJ; ++j)
#pragma unroll
      for (int i = 0; i < 4; ++i)
#pragma unroll
        for (int r = 0; r < 4; ++r)
          slice[(((j * 4 + i) * 4 + r) << 8) + tid] = acc[i][j][r];
    __threadfence();            // release: my stores visible before my signal
    __syncthreads();
    if (tid == 0)
      sLast = (atomicAdd(&cnt[tileIdx], 1) & 1);
    __syncthreads();
    if (!sLast) return;         // first finisher exits; no spinning
    __threadfence();            // acquire: other slice now visible
    other = part + (size_t)(1 - kz) * MN + (size_t)tileIdx * (TM * TN);
  }

  // --- epilogue --- C/D layout: col = lane&15, row = (lane>>4)*4 + r (m89-verified)
#pragma unroll
  for (int j = 0; j < NJ; ++j) {
    const int col = bn + wn + j * 16 + lrow;
    const float bcol = bias[col];
#pragma unroll
    for (int i = 0; i < 4; ++i) {
      const int row0 = bm + wm + i * 16 + lk * 4;
#pragma unroll
      for (int r = 0; r < 4; ++r) {
        const size_t idx = (size_t)(row0 + r) * N + col;
        float v = acc[i][j][r] + bcol;
        if constexpr (SPLITK == 2) v += other[(((j * 4 + i) * 4 + r) << 8) + tid];
        if constexpr (EPI == 0) {
          hOut[idx] = f2bf(tanh_fast(v));
        } else if constexpr (EPI == 1) {
          const float xv = xf_in[idx];
          xacc[idx] = fmaf(aacc, v, xv);
          xb[idx] = f2bf(fmaf(cnext, v, xv));
        } else if constexpr (EPI == 2) {
          const float xv = xf_in[idx];
          xacc[idx] = fmaf(aacc, v, xacc[idx]);
          xb[idx] = f2bf(fmaf(cnext, v, xv));
        } else {
          const float xn = fmaf(aacc, v, xacc[idx]);
          xf_out[idx] = xn;
          xb[idx] = f2bf(xn);
        }
      }
    }
  }
}

__global__ void cvt_kernel(const float* __restrict__ s, unsigned short* __restrict__ d, int n4) {
  int i = blockIdx.x * 256 + threadIdx.x;
  if (i < n4) {
    float4 v = ((const float4*)s)[i];
    ((ushort4*)d)[i] = make_ushort4(f2bf(v.x), f2bf(v.y), f2bf(v.z), f2bf(v.w));
  }
}

__global__ void initx_kernel(const float* __restrict__ s, float* __restrict__ xf,
                             unsigned short* __restrict__ xb, int n4) {
  int i = blockIdx.x * 256 + threadIdx.x;
  if (i < n4) {
    float4 v = ((const float4*)s)[i];
    ((float4*)xf)[i] = v;
    ((ushort4*)xb)[i] = make_ushort4(f2bf(v.x), f2bf(v.y), f2bf(v.z), f2bf(v.w));
  }
}

extern "C" void kernel_launch(void* const* d_in, const int* in_sizes, int n_in,
                              void* d_out, int out_size, void* d_ws, size_t ws_size,
                              hipStream_t stream) {
  const float* x  = (const float*)d_in[0];
  const float* W1 = (const float*)d_in[1];
  const float* b1 = (const float*)d_in[2];
  const float* W2 = (const float*)d_in[3];
  const float* b2 = (const float*)d_in[4];
  const int H = in_sizes[2];            // 4096
  const int D = in_sizes[4];            // 1024
  const int B = in_sizes[0] / D;        // 4096

  // workspace layout: W1b | W2b | xb | hb | xacc | part[2] | cnt  (~104 MB)
  unsigned short* W1b = (unsigned short*)d_ws;
  unsigned short* W2b = W1b + (size_t)H * D;
  unsigned short* xb  = W2b + (size_t)D * H;
  unsigned short* hb  = xb + (size_t)B * D;
  float* xacc = (float*)(hb + (size_t)B * H);
  float* part = xacc + (size_t)B * D;
  int*   cnt  = (int*)(part + 2 * (size_t)B * D);
  float* xf   = (float*)d_out;          // fp32 state lives in d_out

  const size_t need = (size_t)((char*)(cnt + (D / 64) * (B / TM)) - (char*)d_ws);
  const bool splitk = (ws_size >= need);

  const float dt = 1.0f / 64.0f;

  int n4 = (H * D) / 4;
  cvt_kernel<<<dim3((n4 + 255) / 256), dim3(256), 0, stream>>>(W1, W1b, n4);
  cvt_kernel<<<dim3((n4 + 255) / 256), dim3(256), 0, stream>>>(W2, W2b, n4);
  int m4 = (B * D) / 4;
  initx_kernel<<<dim3((m4 + 255) / 256), dim3(256), 0, stream>>>(x, xf, xb, m4);

  dim3 blk(256, 1, 1);
  dim3 g1(H / 128, B / TM, 1);          // 32 x 32, TN=128 BK=32
  dim3 g2s(D / 64, B / TM, 2);          // 16 x 32 x 2, split-K
  dim3 g2f(D / 64, B / TM, 1);          // fallback, no split

#define G1()            gemm_bt<128, 32, 0, 1, 2><<<g1, blk, 0, stream>>>( \
      xb, W1b, b1, D, H, hb, nullptr, nullptr, nullptr, nullptr, 0.f, 0.f, nullptr, nullptr)
#define G2(EPI, aa, cn) do { if (splitk) \
      gemm_bt<64, 64, EPI, 2, 2><<<g2s, blk, 0, stream>>>( \
        hb, W2b, b2, H, D, nullptr, xf, xacc, xf, xb, (aa), (cn), part, cnt); \
    else \
      gemm_bt<64, 64, EPI, 1, 2><<<g2f, blk, 0, stream>>>( \
        hb, W2b, b2, H, D, nullptr, xf, xacc, xf, xb, (aa), (cn), nullptr, nullptr); } while (0)

  for (int s = 0; s < 64; ++s) {
    G1(); G2(1, dt / 6.f, dt / 2.f);    // k1
    G1(); G2(2, dt / 3.f, dt / 2.f);    // k2
    G1(); G2(2, dt / 3.f, dt);          // k3
    G1(); G2(3, dt / 6.f, 0.f);         // k4
  }
#undef G1
#undef G2
}

// Round 6
// 28719.141 us; speedup vs baseline: 2.9256x; 2.8169x over previous
//
#include <hip/hip_runtime.h>
#include <stdint.h>

// RK4 ODE integrator: dx/dt = W2·tanh(W1·x + b1) + b2, 64 steps, t in [0,1].
// B=4096, D=1024, H=4096. bf16 MFMA 16x16x32, fp32 accumulate.
// GEMM1: h = tanh(x@W1^T + b1), TM=128/TN=128/BK=32 (m97 structure, ~3 blk/CU).
// GEMM2: k = h@W2^T + b2 + fused RK4 epilogue. TM=128/TN=64/BK=64, 512 blocks
//        (2 blk/CU, grid-limited) -> explicit LDS double-buffer with raw
//        s_barrier + s_waitcnt vmcnt(6): prefetch loads stay in flight across
//        the barrier (AITER-style), removing the per-iter vmcnt(0) drain.
// R4/R5 lesson: split-K's cross-block combine needs __threadfence (device
//        scope) -> L2 writeback storm on non-coherent XCD L2s -> 80+ ms. Dead.

typedef __attribute__((ext_vector_type(8))) __bf16 bf16x8;
typedef __attribute__((ext_vector_type(4))) float floatx4;

#define TM 128

__device__ __forceinline__ unsigned short f2bf(float f) {
  union { float f; unsigned u; } v; v.f = f;
  unsigned r = v.u + 0x7fffu + ((v.u >> 16) & 1u);  // RNE
  return (unsigned short)(r >> 16);
}

__device__ __forceinline__ float tanh_fast(float x) {
  float cx = fminf(15.0f, fmaxf(-15.0f, x));
  float e = __expf(2.0f * cx);                       // v_exp_f32
  return fmaf(-2.0f, __builtin_amdgcn_rcpf(e + 1.0f), 1.0f);
}

__device__ __forceinline__ void async16(const unsigned short* g, unsigned short* l) {
  // direct global->LDS, 16B/lane; LDS dest = wave-uniform base + lane*16
  __builtin_amdgcn_global_load_lds(
      (__attribute__((address_space(1))) void*)(g),
      (__attribute__((address_space(3))) void*)(l),
      16, 0, 0);
}

// ---------------- GEMM1: h = tanh(x@W1^T + b1), single-buffered m97 ----------
__global__ __launch_bounds__(256, 2) void gemm1(
    const unsigned short* __restrict__ A,   // [M,K] bf16
    const unsigned short* __restrict__ Bw,  // [N,K] bf16 (B^T form)
    const float* __restrict__ bias, int K, int N,
    unsigned short* __restrict__ hOut) {
  constexpr int BKT = 32;
  __shared__ unsigned short As[TM * BKT];
  __shared__ unsigned short Bs[TM * BKT];

  const int tid  = threadIdx.x;
  const int lane = tid & 63;
  const int wv   = tid >> 6;
  const int bm   = blockIdx.y * TM;
  const int bn   = blockIdx.x * TM;

  const int wm   = (wv >> 1) * 64;
  const int wn   = (wv & 1) * 64;
  const int lrow = lane & 15;
  const int lk   = lane >> 4;

  floatx4 acc[4][4];
#pragma unroll
  for (int i = 0; i < 4; ++i)
#pragma unroll
    for (int j = 0; j < 4; ++j) acc[i][j] = (floatx4){0.f, 0.f, 0.f, 0.f};

  const int sr  = lane >> 2;          // 16 rows x 32 cols per call
  const int sc  = (lane & 3) << 3;
  const int arb = wv * 32;

  const unsigned short* pA = A  + (size_t)(bm + arb + sr) * K + sc;
  const unsigned short* pB = Bw + (size_t)(bn + arb + sr) * K + sc;
  const size_t rstep = (size_t)16 * K;

  for (int k0 = 0; k0 < K; k0 += BKT) {
    async16(pA, &As[arb * BKT]);
    async16(pA + rstep, &As[(arb + 16) * BKT]);
    async16(pB, &Bs[arb * BKT]);
    async16(pB + rstep, &Bs[(arb + 16) * BKT]);
    pA += BKT; pB += BKT;
    asm volatile("s_waitcnt vmcnt(0)" ::: "memory");
    __syncthreads();

    bf16x8 aF[4], bF[4];
#pragma unroll
    for (int i = 0; i < 4; ++i)
      aF[i] = *(const bf16x8*)(&As[(wm + i * 16 + lrow) * BKT + lk * 8]);
#pragma unroll
    for (int j = 0; j < 4; ++j)
      bF[j] = *(const bf16x8*)(&Bs[(wn + j * 16 + lrow) * BKT + lk * 8]);
#pragma unroll
    for (int i = 0; i < 4; ++i)
#pragma unroll
      for (int j = 0; j < 4; ++j)
        acc[i][j] = __builtin_amdgcn_mfma_f32_16x16x32_bf16(aF[i], bF[j], acc[i][j], 0, 0, 0);
    __syncthreads();
  }

  // C/D layout: col = lane&15, row = (lane>>4)*4 + r (m89-verified)
#pragma unroll
  for (int j = 0; j < 4; ++j) {
    const int col = bn + wn + j * 16 + lrow;
    const float bcol = bias[col];
#pragma unroll
    for (int i = 0; i < 4; ++i) {
      const int row0 = bm + wm + i * 16 + lk * 4;
#pragma unroll
      for (int r = 0; r < 4; ++r)
        hOut[(size_t)(row0 + r) * N + col] = f2bf(tanh_fast(acc[i][j][r] + bcol));
    }
  }
}

// ------- GEMM2: k = h@W2^T + b2, double-buffered LDS, fused RK4 epilogue -----
// EPI: 1 = first (xacc = xf + aacc*k ; xb = bf16(xf + cnext*k))
//      2 = mid   (xacc += aacc*k    ; xb = bf16(xf + cnext*k))
//      3 = last  (xf = xacc + aacc*k; xb = bf16(xf))
template <int EPI>
__global__ __launch_bounds__(256, 2) void gemm2_db(
    const unsigned short* __restrict__ A,   // [M,K] bf16 (h)
    const unsigned short* __restrict__ Bw,  // [N,K] bf16 (W2, B^T form)
    const float* __restrict__ bias, int K, int N,
    const float* xf_in, float* xacc, float* xf_out, unsigned short* xb,
    float aacc, float cnext) {
  constexpr int TN = 64, BKT = 64;
  __shared__ unsigned short As[2][TM * BKT];   // 2 x 16 KB
  __shared__ unsigned short Bs[2][TN * BKT];   // 2 x 8 KB

  const int tid  = threadIdx.x;
  const int lane = tid & 63;
  const int wv   = tid >> 6;
  const int bm   = blockIdx.y * TM;
  const int bn   = blockIdx.x * TN;

  const int wm   = (wv >> 1) * 64;
  const int wn   = (wv & 1) * 32;
  const int lrow = lane & 15;
  const int lk   = lane >> 4;

  floatx4 acc[4][2];
#pragma unroll
  for (int i = 0; i < 4; ++i)
#pragma unroll
    for (int j = 0; j < 2; ++j) acc[i][j] = (floatx4){0.f, 0.f, 0.f, 0.f};

  // staging: 8 rows x 64 cols per async16 call; A 4 calls, B 2 calls per wave
  const int sr  = lane >> 3;
  const int sc  = (lane & 7) << 3;
  const int arb = wv * 32;
  const int brb = wv * 16;

  const unsigned short* pA = A  + (size_t)(bm + arb + sr) * K + sc;
  const unsigned short* pB = Bw + (size_t)(bn + brb + sr) * K + sc;

  const int nIter = K / BKT;            // 64

#define STAGE(buf)                                                        \
  do {                                                                    \
    _Pragma("unroll")                                                     \
    for (int c = 0; c < 4; ++c)                                           \
      async16(pA + (size_t)(c * 8) * K, &As[buf][(arb + c * 8) * BKT]);   \
    _Pragma("unroll")                                                     \
    for (int c = 0; c < 2; ++c)                                           \
      async16(pB + (size_t)(c * 8) * K, &Bs[buf][(brb + c * 8) * BKT]);   \
    pA += BKT; pB += BKT;                                                 \
  } while (0)

  STAGE(0);                             // prologue
  for (int i = 0; i < nIter; ++i) {
    const int cur = i & 1;
    if (i + 1 < nIter) {
      STAGE(!cur);                      // prefetch next tile into other buffer
      // wait only for the 6 loads of tile i (issued last iter); the 6 just
      // issued remain in flight across the barrier (never vmcnt(0) mid-loop)
      asm volatile("s_waitcnt vmcnt(6)" ::: "memory");
    } else {
      asm volatile("s_waitcnt vmcnt(0)" ::: "memory");
    }
    asm volatile("s_barrier" ::: "memory");   // raw: no compiler vmcnt(0) drain

#pragma unroll
    for (int kh = 0; kh < 2; ++kh) {
      bf16x8 aF[4], bF[2];
#pragma unroll
      for (int ii = 0; ii < 4; ++ii)
        aF[ii] = *(const bf16x8*)(&As[cur][(wm + ii * 16 + lrow) * BKT + kh * 32 + lk * 8]);
#pragma unroll
      for (int j = 0; j < 2; ++j)
        bF[j] = *(const bf16x8*)(&Bs[cur][(wn + j * 16 + lrow) * BKT + kh * 32 + lk * 8]);
#pragma unroll
      for (int ii = 0; ii < 4; ++ii)
#pragma unroll
        for (int j = 0; j < 2; ++j)
          acc[ii][j] = __builtin_amdgcn_mfma_f32_16x16x32_bf16(aF[ii], bF[j], acc[ii][j], 0, 0, 0);
    }
    asm volatile("s_barrier" ::: "memory");   // all waves done reading cur
  }
#undef STAGE

  // epilogue — C/D layout: col = lane&15, row = (lane>>4)*4 + r
#pragma unroll
  for (int j = 0; j < 2; ++j) {
    const int col = bn + wn + j * 16 + lrow;
    const float bcol = bias[col];
#pragma unroll
    for (int i = 0; i < 4; ++i) {
      const int row0 = bm + wm + i * 16 + lk * 4;
#pragma unroll
      for (int r = 0; r < 4; ++r) {
        const float v = acc[i][j][r] + bcol;
        const size_t idx = (size_t)(row0 + r) * N + col;
        if constexpr (EPI == 1) {
          const float xv = xf_in[idx];
          xacc[idx] = fmaf(aacc, v, xv);
          xb[idx] = f2bf(fmaf(cnext, v, xv));
        } else if constexpr (EPI == 2) {
          const float xv = xf_in[idx];
          xacc[idx] = fmaf(aacc, v, xacc[idx]);
          xb[idx] = f2bf(fmaf(cnext, v, xv));
        } else {
          const float xn = fmaf(aacc, v, xacc[idx]);
          xf_out[idx] = xn;
          xb[idx] = f2bf(xn);
        }
      }
    }
  }
}

__global__ void cvt_kernel(const float* __restrict__ s, unsigned short* __restrict__ d, int n4) {
  int i = blockIdx.x * 256 + threadIdx.x;
  if (i < n4) {
    float4 v = ((const float4*)s)[i];
    ((ushort4*)d)[i] = make_ushort4(f2bf(v.x), f2bf(v.y), f2bf(v.z), f2bf(v.w));
  }
}

__global__ void initx_kernel(const float* __restrict__ s, float* __restrict__ xf,
                             unsigned short* __restrict__ xb, int n4) {
  int i = blockIdx.x * 256 + threadIdx.x;
  if (i < n4) {
    float4 v = ((const float4*)s)[i];
    ((float4*)xf)[i] = v;
    ((ushort4*)xb)[i] = make_ushort4(f2bf(v.x), f2bf(v.y), f2bf(v.z), f2bf(v.w));
  }
}

extern "C" void kernel_launch(void* const* d_in, const int* in_sizes, int n_in,
                              void* d_out, int out_size, void* d_ws, size_t ws_size,
                              hipStream_t stream) {
  const float* x  = (const float*)d_in[0];
  const float* W1 = (const float*)d_in[1];
  const float* b1 = (const float*)d_in[2];
  const float* W2 = (const float*)d_in[3];
  const float* b2 = (const float*)d_in[4];
  const int H = in_sizes[2];            // 4096
  const int D = in_sizes[4];            // 1024
  const int B = in_sizes[0] / D;        // 4096

  // workspace layout (~72 MB): W1b | W2b | xb | hb | xacc
  unsigned short* W1b = (unsigned short*)d_ws;
  unsigned short* W2b = W1b + (size_t)H * D;
  unsigned short* xb  = W2b + (size_t)D * H;
  unsigned short* hb  = xb + (size_t)B * D;
  float* xacc = (float*)(hb + (size_t)B * H);
  float* xf   = (float*)d_out;          // fp32 state lives in d_out

  const float dt = 1.0f / 64.0f;

  int n4 = (H * D) / 4;
  cvt_kernel<<<dim3((n4 + 255) / 256), dim3(256), 0, stream>>>(W1, W1b, n4);
  cvt_kernel<<<dim3((n4 + 255) / 256), dim3(256), 0, stream>>>(W2, W2b, n4);
  int m4 = (B * D) / 4;
  initx_kernel<<<dim3((m4 + 255) / 256), dim3(256), 0, stream>>>(x, xf, xb, m4);

  dim3 blk(256, 1, 1);
  dim3 g1(H / 128, B / TM, 1);          // 32 x 32
  dim3 g2(D / 64,  B / TM, 1);          // 16 x 32

  for (int s = 0; s < 64; ++s) {
    // k1
    gemm1<<<g1, blk, 0, stream>>>(xb, W1b, b1, D, H, hb);
    gemm2_db<1><<<g2, blk, 0, stream>>>(hb, W2b, b2, H, D, xf, xacc, xf, xb, dt / 6.f, dt / 2.f);
    // k2
    gemm1<<<g1, blk, 0, stream>>>(xb, W1b, b1, D, H, hb);
    gemm2_db<2><<<g2, blk, 0, stream>>>(hb, W2b, b2, H, D, xf, xacc, xf, xb, dt / 3.f, dt / 2.f);
    // k3
    gemm1<<<g1, blk, 0, stream>>>(xb, W1b, b1, D, H, hb);
    gemm2_db<2><<<g2, blk, 0, stream>>>(hb, W2b, b2, H, D, xf, xacc, xf, xb, dt / 3.f, dt);
    // k4
    gemm1<<<g1, blk, 0, stream>>>(xb, W1b, b1, D, H, hb);
    gemm2_db<3><<<g2, blk, 0, stream>>>(hb, W2b, b2, H, D, xf, xacc, xf, xb, dt / 6.f, 0.f);
  }
}